// Round 4
// baseline (77.655 us; speedup 1.0000x reference)
//
#include <hip/hip_runtime.h>
#include <math.h>

typedef __attribute__((ext_vector_type(8))) short bf16x8;
typedef __attribute__((ext_vector_type(4))) float f32x4;
typedef __attribute__((ext_vector_type(4))) int i32x4;
typedef __attribute__((ext_vector_type(4))) unsigned short u16x4;

#define LOG2E 1.4426950408889634f
#define LN2   0.6931471805599453f
#define FTINY 1.1754943508222875e-38f
#define MOFF  16.0f   // fixed base-2 LSE offset; logits provably < 12

constexpr int Dd = 64;
constexpr int Bb = 4096;
constexpr int Ss = 40960;
constexpr int BN = 256;               // batch cols per block
constexpr int SCHUNK = 128;           // s-rows per LDS chunk (16 KiB)
constexpr int STILES = 32;
constexpr int SPB = Ss / STILES;      // 1280
constexpr int NCHUNK = SPB / SCHUNK;  // 10
constexpr int NBLOCKS = STILES * (Bb / BN);  // 512

constexpr int GATHER_BLOCKS = Ss / 16;   // 2560
constexpr int C2_BLOCKS = Ss / 256;      // 160
constexpr int POS_BLOCKS = Bb / 64;      // 64

static __device__ __forceinline__ unsigned short f2bf(float x) {
    unsigned int u = __float_as_uint(x);
    u += 0x7fffu + ((u >> 16) & 1u);   // RNE
    return (unsigned short)(u >> 16);
}

// KEEP powf(1.0f-p, T): must reproduce the reference's fp32 quantization of (1-p).
static __device__ __forceinline__ float neg_log_expected(int id, float invLogV1, float T) {
    float f = (float)id;
    float p = log1pf(1.0f / (f + 1.0f)) * invLogV1;
    float pw = powf(1.0f - p, T);
    float se = fmaxf(1.0f - pw, FTINY);
    return -logf(se);
}

// ---- K1: gather Ebf | zero bitmap+counters | c2' | pos2 (exact fp32 dot) ----
__global__ void k_prep(const float* __restrict__ user, const float* __restrict__ item,
                       const float* __restrict__ bias, const int* __restrict__ sampled,
                       const int* __restrict__ posids, const int* __restrict__ ntries,
                       unsigned short* __restrict__ Ebf, float* __restrict__ c2,
                       float* __restrict__ pos2, unsigned int* __restrict__ bm,
                       unsigned int* __restrict__ ctr, float invLogV1, int nbmw, int zb) {
    const int bid = blockIdx.x, tid = threadIdx.x;
    if (bid < GATHER_BLOCKS) {
        const int ri = tid >> 4, c = tid & 15;
        const int s = bid * 16 + ri;
        const int sid = sampled[s];
        f32x4 v = *(const f32x4*)(item + (size_t)sid * Dd + c * 4);
        u16x4 o;
        o[0] = f2bf(v[0]); o[1] = f2bf(v[1]); o[2] = f2bf(v[2]); o[3] = f2bf(v[3]);
        *(u16x4*)(Ebf + (size_t)s * Dd + c * 4) = o;
    } else if (bid < GATHER_BLOCKS + zb) {
        const int z = bid - GATHER_BLOCKS;
        const int base = (z * 256 + tid) * 4;
        if (base + 3 < nbmw) {
            i32x4 zz = {0, 0, 0, 0};
            *(i32x4*)((int*)bm + base) = zz;
        } else {
            for (int i = base; i < nbmw; ++i) bm[i] = 0u;
        }
        if (z == 0 && tid < 18) ctr[tid] = 0u;   // [0]=scat, [1..16]=btile, [17]=final
    } else if (bid < GATHER_BLOCKS + zb + C2_BLOCKS) {
        const int s = (bid - GATHER_BLOCKS - zb) * 256 + tid;
        const int sid = sampled[s];
        const float T = (float)ntries[0];
        c2[s] = (bias[sid] + neg_log_expected(sid, invLogV1, T)) * LOG2E - MOFF;
    } else {
        const int pbk = bid - GATHER_BLOCKS - zb - C2_BLOCKS;
        const int sub = tid & 3, b = pbk * 64 + (tid >> 2);
        const int pid = posids[b];
        const f32x4* up = (const f32x4*)(user + (size_t)b * Dd + sub * 16);
        const f32x4* ep = (const f32x4*)(item + (size_t)pid * Dd + sub * 16);
        f32x4 dv = {0.f, 0.f, 0.f, 0.f};
        #pragma unroll
        for (int i = 0; i < 4; ++i) {
            f32x4 uu = up[i], ee = ep[i];
            dv[0] = fmaf(uu[0], ee[0], dv[0]); dv[1] = fmaf(uu[1], ee[1], dv[1]);
            dv[2] = fmaf(uu[2], ee[2], dv[2]); dv[3] = fmaf(uu[3], ee[3], dv[3]);
        }
        float d = (dv[0] + dv[1]) + (dv[2] + dv[3]);
        d += __shfl_xor(d, 1); d += __shfl_xor(d, 2);
        if (sub == 0) {
            const float T = (float)ntries[0];
            pos2[b] = (d + bias[pid] + neg_log_expected(pid, invLogV1, T)) * LOG2E;
        }
    }
}

// ---- K2: bitmap scatter + fused GEMM-LSE + ticket finalize ----
__global__ __launch_bounds__(256) void ssl_main(
    const unsigned short* __restrict__ Ebf, const float* __restrict__ user,
    const float* __restrict__ c2, const int* __restrict__ sampled,
    const int* __restrict__ posids, const float* __restrict__ pos2,
    unsigned int* __restrict__ bm, unsigned int* __restrict__ ctr,
    float* __restrict__ partials, float* __restrict__ bsums, float* __restrict__ out)
{
    __shared__ __align__(16) unsigned short lds[SCHUNK * Dd];   // 16 KiB
    __shared__ float redbuf[4];
    __shared__ unsigned int fin_flag;
    const int tid = threadIdx.x;
    const int w = tid >> 6, l = tid & 63;
    const int g16 = l >> 4, l16 = l & 15;
    const int stile = blockIdx.x, btile = blockIdx.y;
    const int fid = stile + STILES * btile;

    // bitmap scatter: 80 ids per block (512 x 80 = 40960)
    if (tid < 80) {
        const int sid = sampled[fid * 80 + tid];
        atomicOr(&bm[sid >> 5], 1u << (sid & 31));
    }
    __syncthreads();
    if (tid == 0) { __threadfence(); atomicAdd(&ctr[0], 1u); }

    const int s0 = stile * SPB;
    const int colb = btile * BN + w * 64;

    // U fragments: fp32 -> bf16*LOG2E in-register (no Ubf array)
    bf16x8 bf[4][2];
    #pragma unroll
    for (int g = 0; g < 4; ++g) {
        const float* up = user + (size_t)(colb + g * 16 + l16) * Dd + g16 * 8;
        f32x4 u0 = *(const f32x4*)(up);
        f32x4 u1 = *(const f32x4*)(up + 4);
        f32x4 u2 = *(const f32x4*)(up + 32);
        f32x4 u3 = *(const f32x4*)(up + 36);
        bf16x8 f0, f1;
        f0[0] = (short)f2bf(u0[0] * LOG2E); f0[1] = (short)f2bf(u0[1] * LOG2E);
        f0[2] = (short)f2bf(u0[2] * LOG2E); f0[3] = (short)f2bf(u0[3] * LOG2E);
        f0[4] = (short)f2bf(u1[0] * LOG2E); f0[5] = (short)f2bf(u1[1] * LOG2E);
        f0[6] = (short)f2bf(u1[2] * LOG2E); f0[7] = (short)f2bf(u1[3] * LOG2E);
        f1[0] = (short)f2bf(u2[0] * LOG2E); f1[1] = (short)f2bf(u2[1] * LOG2E);
        f1[2] = (short)f2bf(u2[2] * LOG2E); f1[3] = (short)f2bf(u2[3] * LOG2E);
        f1[4] = (short)f2bf(u3[0] * LOG2E); f1[5] = (short)f2bf(u3[1] * LOG2E);
        f1[6] = (short)f2bf(u3[2] * LOG2E); f1[7] = (short)f2bf(u3[3] * LOG2E);
        bf[g][0] = f0; bf[g][1] = f1;
    }

    float rl0 = 0.f, rl1 = 0.f, rl2 = 0.f, rl3 = 0.f;

    // staging: 4 x 16B per thread, linear LDS dest, source pre-swizzled
    const int srow = tid >> 3, scs = tid & 7;
    const int csrc = scs ^ (srow & 7);
    const unsigned short* stgp = Ebf + (size_t)(s0 + srow) * Dd + csrc * 8;
    bf16x8 stg0 = *(const bf16x8*)(stgp);
    bf16x8 stg1 = *(const bf16x8*)(stgp + 32 * Dd);
    bf16x8 stg2 = *(const bf16x8*)(stgp + 64 * Dd);
    bf16x8 stg3 = *(const bf16x8*)(stgp + 96 * Dd);
    const float* c2b = c2 + s0 + g16 * 4;

    for (int ch = 0; ch < NCHUNK; ++ch) {
        __syncthreads();
        *(bf16x8*)(lds + tid * 8)            = stg0;
        *(bf16x8*)(lds + tid * 8 + 32 * Dd)  = stg1;
        *(bf16x8*)(lds + tid * 8 + 64 * Dd)  = stg2;
        *(bf16x8*)(lds + tid * 8 + 96 * Dd)  = stg3;
        if (ch + 1 < NCHUNK) {
            const unsigned short* np = stgp + (size_t)(ch + 1) * SCHUNK * Dd;
            stg0 = *(const bf16x8*)(np);
            stg1 = *(const bf16x8*)(np + 32 * Dd);
            stg2 = *(const bf16x8*)(np + 64 * Dd);
            stg3 = *(const bf16x8*)(np + 96 * Dd);
        }
        __syncthreads();

        const float* c2c = c2b + ch * SCHUNK;
        #pragma unroll
        for (int t = 0; t < 8; ++t) {
            const int r = t * 16 + l16;
            const int sw = r & 7;
            const bf16x8 a0 = *(const bf16x8*)(lds + r * Dd + (((g16    ) ^ sw) << 3));
            const bf16x8 a1 = *(const bf16x8*)(lds + r * Dd + (((g16 + 4) ^ sw) << 3));
            const f32x4 cc = *(const f32x4*)(c2c + t * 16);
            {
                f32x4 acc = __builtin_amdgcn_mfma_f32_16x16x32_bf16(a0, bf[0][0], cc, 0, 0, 0);
                acc = __builtin_amdgcn_mfma_f32_16x16x32_bf16(a1, bf[0][1], acc, 0, 0, 0);
                rl0 += (__builtin_amdgcn_exp2f(acc[0]) + __builtin_amdgcn_exp2f(acc[1]))
                     + (__builtin_amdgcn_exp2f(acc[2]) + __builtin_amdgcn_exp2f(acc[3]));
            }
            {
                f32x4 acc = __builtin_amdgcn_mfma_f32_16x16x32_bf16(a0, bf[1][0], cc, 0, 0, 0);
                acc = __builtin_amdgcn_mfma_f32_16x16x32_bf16(a1, bf[1][1], acc, 0, 0, 0);
                rl1 += (__builtin_amdgcn_exp2f(acc[0]) + __builtin_amdgcn_exp2f(acc[1]))
                     + (__builtin_amdgcn_exp2f(acc[2]) + __builtin_amdgcn_exp2f(acc[3]));
            }
            {
                f32x4 acc = __builtin_amdgcn_mfma_f32_16x16x32_bf16(a0, bf[2][0], cc, 0, 0, 0);
                acc = __builtin_amdgcn_mfma_f32_16x16x32_bf16(a1, bf[2][1], acc, 0, 0, 0);
                rl2 += (__builtin_amdgcn_exp2f(acc[0]) + __builtin_amdgcn_exp2f(acc[1]))
                     + (__builtin_amdgcn_exp2f(acc[2]) + __builtin_amdgcn_exp2f(acc[3]));
            }
            {
                f32x4 acc = __builtin_amdgcn_mfma_f32_16x16x32_bf16(a0, bf[3][0], cc, 0, 0, 0);
                acc = __builtin_amdgcn_mfma_f32_16x16x32_bf16(a1, bf[3][1], acc, 0, 0, 0);
                rl3 += (__builtin_amdgcn_exp2f(acc[0]) + __builtin_amdgcn_exp2f(acc[1]))
                     + (__builtin_amdgcn_exp2f(acc[2]) + __builtin_amdgcn_exp2f(acc[3]));
            }
        }
    }

    // sum across 4 lane-groups (same col, different s-rows)
    rl0 += __shfl_xor(rl0, 16); rl0 += __shfl_xor(rl0, 32);
    rl1 += __shfl_xor(rl1, 16); rl1 += __shfl_xor(rl1, 32);
    rl2 += __shfl_xor(rl2, 16); rl2 += __shfl_xor(rl2, 32);
    rl3 += __shfl_xor(rl3, 16); rl3 += __shfl_xor(rl3, 32);
    if (l < 16) {
        partials[(size_t)(colb +  0 + l16) * STILES + stile] = rl0;
        partials[(size_t)(colb + 16 + l16) * STILES + stile] = rl1;
        partials[(size_t)(colb + 32 + l16) * STILES + stile] = rl2;
        partials[(size_t)(colb + 48 + l16) * STILES + stile] = rl3;
    }

    // ----- ticket: last stile-block for this btile finalizes its 256 cols -----
    if (tid == 0) {
        __threadfence();
        unsigned int old = atomicAdd(&ctr[1 + btile], 1u);
        fin_flag = (old == (unsigned)(STILES - 1)) ? 1u : 0u;
    }
    __syncthreads();
    if (fin_flag == 0u) return;

    if (tid == 0) {   // ensure all bitmap scatters landed (termination-safe)
        while (atomicAdd(&ctr[0], 0u) < (unsigned)NBLOCKS) __builtin_amdgcn_s_sleep(2);
    }
    __syncthreads();

    const int col = btile * BN + tid;
    const float* pp = partials + (size_t)col * STILES;
    float S = 0.f;
    #pragma unroll
    for (int i = 0; i < 8; ++i) {
        f32x4 p = *(const f32x4*)(pp + i * 4);
        S += ((p[0] + p[1]) + (p[2] + p[3]));
    }
    const float pb2 = pos2[col];
    const int pid = posids[col];
    const bool hit = (bm[pid >> 5] >> (pid & 31)) & 1u;
    // hit term == exp2(pb2-MOFF) exactly (hit row IS item[pid]); masked col cancels pos col
    if (!hit) S += __builtin_amdgcn_exp2f(pb2 - MOFF);
    float loss = (MOFF + log2f(S) - pb2) * LN2;

    #pragma unroll
    for (int off = 1; off < 64; off <<= 1) loss += __shfl_xor(loss, off);
    if (l == 0) redbuf[w] = loss;
    __syncthreads();
    if (tid == 0) {
        bsums[btile] = (redbuf[0] + redbuf[1]) + (redbuf[2] + redbuf[3]);
        __threadfence();
        if (atomicAdd(&ctr[17], 1u) == (unsigned)(Bb / BN - 1)) {
            __threadfence();
            float tot = 0.f;
            for (int i = 0; i < Bb / BN; ++i) tot += bsums[i];
            out[0] = tot / (float)Bb;
        }
    }
}

extern "C" void kernel_launch(void* const* d_in, const int* in_sizes, int n_in,
                              void* d_out, int out_size, void* d_ws, size_t ws_size,
                              hipStream_t stream) {
    (void)n_in; (void)out_size; (void)ws_size;
    const float* user    = (const float*)d_in[0];
    const float* item    = (const float*)d_in[1];
    const float* bias    = (const float*)d_in[2];
    const int*   posids  = (const int*)d_in[3];
    const int*   sampled = (const int*)d_in[4];
    const int*   ntries  = (const int*)d_in[5];
    float* out = (float*)d_out;

    const int V = in_sizes[2];
    const float invLogV1 = 1.0f / logf((float)V + 1.0f);
    const int nbmw = (V + 31) / 32;
    const int zb = (nbmw + 1023) / 1024;

    char* p = (char*)d_ws;
    auto alloc = [&](size_t bytes) {
        char* r = p;
        p += (bytes + 255) & ~(size_t)255;
        return r;
    };
    unsigned short* Ebf     = (unsigned short*)alloc((size_t)Ss * Dd * 2);
    float*          c2      = (float*)alloc((size_t)Ss * 4);
    float*          pos2    = (float*)alloc((size_t)Bb * 4);
    float*          partial = (float*)alloc((size_t)Bb * STILES * 4);
    unsigned int*   bm      = (unsigned int*)alloc((size_t)nbmw * 4);
    float*          bsums   = (float*)alloc(64 * 4);
    unsigned int*   ctr     = (unsigned int*)alloc(256);

    k_prep<<<GATHER_BLOCKS + zb + C2_BLOCKS + POS_BLOCKS, 256, 0, stream>>>(
        user, item, bias, sampled, posids, ntries, Ebf, c2, pos2, bm, ctr,
        invLogV1, nbmw, zb);
    ssl_main<<<dim3(STILES, Bb / BN), 256, 0, stream>>>(
        Ebf, user, c2, sampled, posids, pos2, bm, ctr, partial, bsums, out);
}

// Round 5
// 58.144 us; speedup vs baseline: 1.3356x; 1.3356x over previous
//
#include <hip/hip_runtime.h>
#include <math.h>

typedef __attribute__((ext_vector_type(8))) short bf16x8;
typedef __attribute__((ext_vector_type(4))) float f32x4;
typedef __attribute__((ext_vector_type(4))) int i32x4;
typedef __attribute__((ext_vector_type(4))) unsigned short u16x4;

#define LOG2E 1.4426950408889634f
#define LN2   0.6931471805599453f
#define FTINY 1.1754943508222875e-38f
#define MOFF  16.0f   // fixed base-2 LSE offset; logits provably < 12

// Problem constants (fixed by the reference)
constexpr int Dd = 64;
constexpr int Bb = 4096;
constexpr int Ss = 40960;
constexpr int BN = 256;              // batch cols per block in main kernel
constexpr int SCHUNK = 64;           // s-rows per LDS chunk
constexpr int STILES = 32;           // grid.x of main kernel
constexpr int SPB = Ss / STILES;     // 1280 s-rows per block
constexpr int NCHUNK = SPB / SCHUNK; // 20

// K1 grid segments
constexpr int SAMP_BLOCKS = Ss / 16;             // 2560
constexpr int USER_BLOCKS = (Bb * Dd / 4) / 256; // 256
constexpr int C2_BLOCKS   = Ss / 256;            // 160

static __device__ __forceinline__ unsigned short f2bf(float x) {
    unsigned int u = __float_as_uint(x);
    u += 0x7fffu + ((u >> 16) & 1u);   // RNE
    return (unsigned short)(u >> 16);
}

// KEEP powf(1.0f-p, T): must reproduce the reference's fp32 quantization of (1-p).
static __device__ __forceinline__ float neg_log_expected(int id, float invLogV1, float T) {
    float f = (float)id;
    float p = log1pf(1.0f / (f + 1.0f)) * invLogV1;
    float pw = powf(1.0f - p, T);
    float se = fmaxf(1.0f - pw, FTINY);
    return -logf(se);
}

// ---- K1: samp gather->bf16 | bitmap zero + cnt | user->bf16*LOG2E | c2' + bitmap set ----
__global__ void k_prep(const float* __restrict__ user, const float* __restrict__ item,
                       const float* __restrict__ bias, const int* __restrict__ sampled,
                       const int* __restrict__ ntries,
                       unsigned short* __restrict__ Ebf, unsigned short* __restrict__ Ubf,
                       float* __restrict__ c2, unsigned int* __restrict__ bm,
                       unsigned int* __restrict__ cnt, float invLogV1, int nbmw, int zb) {
    const int bid = blockIdx.x, tid = threadIdx.x;
    if (bid < SAMP_BLOCKS) {
        const int ri = tid >> 4, c = tid & 15;
        const int s = bid * 16 + ri;
        const int sid = sampled[s];
        f32x4 v = *(const f32x4*)(item + (size_t)sid * Dd + c * 4);
        u16x4 o;
        o[0] = f2bf(v[0]); o[1] = f2bf(v[1]); o[2] = f2bf(v[2]); o[3] = f2bf(v[3]);
        *(u16x4*)(Ebf + (size_t)s * Dd + c * 4) = o;
    } else if (bid < SAMP_BLOCKS + zb) {
        const int z = bid - SAMP_BLOCKS;
        if (z == 0 && tid == 0) *cnt = 0u;
        const int base = (z * 256 + tid) * 4;
        if (base + 3 < nbmw) {
            i32x4 zz = {0, 0, 0, 0};
            *(i32x4*)((int*)bm + base) = zz;
        } else {
            for (int i = base; i < nbmw; ++i) bm[i] = 0u;
        }
    } else if (bid < SAMP_BLOCKS + zb + USER_BLOCKS) {
        const int i = (bid - SAMP_BLOCKS - zb) * 256 + tid;
        f32x4 v = *(const f32x4*)(user + (size_t)i * 4);
        u16x4 o;
        o[0] = f2bf(v[0] * LOG2E); o[1] = f2bf(v[1] * LOG2E);
        o[2] = f2bf(v[2] * LOG2E); o[3] = f2bf(v[3] * LOG2E);
        *(u16x4*)(Ubf + (size_t)i * 4) = o;
    } else {
        const int s = (bid - SAMP_BLOCKS - zb - USER_BLOCKS) * 256 + tid;
        const int sid = sampled[s];
        const float T = (float)ntries[0];
        c2[s] = (bias[sid] + neg_log_expected(sid, invLogV1, T)) * LOG2E - MOFF;
        atomicOr(&bm[sid >> 5], 1u << (sid & 31));   // membership bit
    }
}

// ---- K2: fused GEMM (base-2, c2' in accumulator) + fixed-offset sum-of-exp2 partials ----
// 4 waves x 64 cols each (halves redundant LDS A-fragment reads vs 8x32).
__global__ __launch_bounds__(256) void ssl_main(
    const unsigned short* __restrict__ Ebf, const unsigned short* __restrict__ Ubf,
    const float* __restrict__ c2, float* __restrict__ partials)
{
    __shared__ __align__(16) unsigned short lds[SCHUNK * Dd];   // 8 KiB
    const int tid = threadIdx.x;
    const int w = tid >> 6, l = tid & 63;
    const int g16 = l >> 4, l16 = l & 15;
    const int stile = blockIdx.x, btile = blockIdx.y;

    const int s0 = stile * SPB;
    const int colb = btile * BN + w * 64;   // 64 batch cols per wave
    // 8 B-fragments (U rows, pre-scaled by LOG2E): 4 col-groups x 2 K-halves
    bf16x8 bf[4][2];
    #pragma unroll
    for (int g = 0; g < 4; ++g) {
        const unsigned short* up = Ubf + (size_t)(colb + g * 16 + l16) * Dd + g16 * 8;
        bf[g][0] = *(const bf16x8*)(up);
        bf[g][1] = *(const bf16x8*)(up + 32);
    }

    float rl0 = 0.f, rl1 = 0.f, rl2 = 0.f, rl3 = 0.f;

    // staging: 256 threads x 2 x 16B pieces, linear LDS, source pre-swizzled
    const int srow = tid >> 3, scs = tid & 7;
    const int csrc = scs ^ (srow & 7);
    const unsigned short* stgp = Ebf + (size_t)(s0 + srow) * Dd + csrc * 8;
    bf16x8 stg0 = *(const bf16x8*)stgp;
    bf16x8 stg1 = *(const bf16x8*)(stgp + 32 * Dd);   // row+32: same swizzle (32%8==0)
    const float* c2b = c2 + s0 + g16 * 4;

    for (int ch = 0; ch < NCHUNK; ++ch) {
        __syncthreads();                            // previous chunk consumed
        *(bf16x8*)(lds + tid * 8) = stg0;           // rows 0..31
        *(bf16x8*)(lds + tid * 8 + 32 * Dd) = stg1; // rows 32..63
        if (ch + 1 < NCHUNK) {
            stg0 = *(const bf16x8*)(stgp + (size_t)(ch + 1) * SCHUNK * Dd);
            stg1 = *(const bf16x8*)(stgp + (size_t)(ch + 1) * SCHUNK * Dd + 32 * Dd);
        }
        const float* c2c = c2b + ch * SCHUNK;
        f32x4 cc0 = *(const f32x4*)(c2c);
        f32x4 cc1 = *(const f32x4*)(c2c + 16);
        f32x4 cc2 = *(const f32x4*)(c2c + 32);
        f32x4 cc3 = *(const f32x4*)(c2c + 48);
        __syncthreads();

        #pragma unroll
        for (int t = 0; t < 4; ++t) {
            const int r = t * 16 + l16;
            const int sw = r & 7;
            const bf16x8 a0 = *(const bf16x8*)(lds + r * Dd + (((g16    ) ^ sw) << 3));
            const bf16x8 a1 = *(const bf16x8*)(lds + r * Dd + (((g16 + 4) ^ sw) << 3));
            const f32x4 cc = (t == 0) ? cc0 : (t == 1) ? cc1 : (t == 2) ? cc2 : cc3;
            #pragma unroll
            for (int g = 0; g < 4; ++g) {
                f32x4 acc = cc;   // c2' (incl. -MOFF) rides in the accumulator
                acc = __builtin_amdgcn_mfma_f32_16x16x32_bf16(a0, bf[g][0], acc, 0, 0, 0);
                acc = __builtin_amdgcn_mfma_f32_16x16x32_bf16(a1, bf[g][1], acc, 0, 0, 0);
                // no max tracking: logits - MOFF are in [-20, -4]; exact fp32 sums
                float e = (__builtin_amdgcn_exp2f(acc[0]) + __builtin_amdgcn_exp2f(acc[1]))
                        + (__builtin_amdgcn_exp2f(acc[2]) + __builtin_amdgcn_exp2f(acc[3]));
                if      (g == 0) rl0 += e;
                else if (g == 1) rl1 += e;
                else if (g == 2) rl2 += e;
                else             rl3 += e;
            }
        }
    }

    // sum across the 4 lane-groups (same col, different s-rows): pure adds
    rl0 += __shfl_xor(rl0, 16); rl0 += __shfl_xor(rl0, 32);
    rl1 += __shfl_xor(rl1, 16); rl1 += __shfl_xor(rl1, 32);
    rl2 += __shfl_xor(rl2, 16); rl2 += __shfl_xor(rl2, 32);
    rl3 += __shfl_xor(rl3, 16); rl3 += __shfl_xor(rl3, 32);
    if (l < 16) {
        partials[(size_t)(colb +  0 + l16) * STILES + stile] = rl0;
        partials[(size_t)(colb + 16 + l16) * STILES + stile] = rl1;
        partials[(size_t)(colb + 32 + l16) * STILES + stile] = rl2;
        partials[(size_t)(colb + 48 + l16) * STILES + stile] = rl3;
    }
}

// ---- K3: finalize (4 lanes per row) + last-block mean -> out ----
__global__ void k_final(const float* __restrict__ user, const float* __restrict__ item,
                        const float* __restrict__ bias, const int* __restrict__ posids,
                        const int* __restrict__ ntries, const float* __restrict__ partials,
                        const unsigned int* __restrict__ bm,
                        float* __restrict__ bsums, unsigned int* __restrict__ cnt,
                        float* __restrict__ out, float invLogV1) {
    const int tid = threadIdx.x, sub = tid & 3;
    const int b = blockIdx.x * 64 + (tid >> 2);
    const int pid = posids[b];
    const float T = (float)ntries[0];
    // exact fp32 dot(u_b, item[pid]), 16 elems per lane
    const f32x4* up = (const f32x4*)(user + (size_t)b * Dd + sub * 16);
    const f32x4* ep = (const f32x4*)(item + (size_t)pid * Dd + sub * 16);
    f32x4 dv = {0.f, 0.f, 0.f, 0.f};
    #pragma unroll
    for (int i = 0; i < 4; ++i) {
        f32x4 uu = up[i], ee = ep[i];
        dv[0] = fmaf(uu[0], ee[0], dv[0]); dv[1] = fmaf(uu[1], ee[1], dv[1]);
        dv[2] = fmaf(uu[2], ee[2], dv[2]); dv[3] = fmaf(uu[3], ee[3], dv[3]);
    }
    float d = (dv[0] + dv[1]) + (dv[2] + dv[3]);
    d += __shfl_xor(d, 1); d += __shfl_xor(d, 2);
    // sum of 32 partials, 8 per lane
    const float* pp = partials + (size_t)b * STILES + sub * 8;
    f32x4 p0 = *(const f32x4*)pp, p1 = *(const f32x4*)(pp + 4);
    float S = ((p0[0] + p0[1]) + (p0[2] + p0[3])) + ((p1[0] + p1[1]) + (p1[2] + p1[3]));
    S += __shfl_xor(S, 1); S += __shfl_xor(S, 2);

    const float pb2 = (d + bias[pid] + neg_log_expected(pid, invLogV1, T)) * LOG2E;
    // accidental hit: hit row IS item[pid] -> its term cancels the pos column exactly
    const bool hit = (bm[pid >> 5] >> (pid & 31)) & 1u;
    if (!hit) S += __builtin_amdgcn_exp2f(pb2 - MOFF);
    float loss = (MOFF + log2f(S) - pb2) * LN2; // each b counted 4x (div by 4 at end)

    #pragma unroll
    for (int off = 1; off < 64; off <<= 1) loss += __shfl_xor(loss, off);
    __shared__ float wsum[4];
    if ((tid & 63) == 0) wsum[tid >> 6] = loss;
    __syncthreads();
    if (tid == 0) {
        bsums[blockIdx.x] = wsum[0] + wsum[1] + wsum[2] + wsum[3];
        __threadfence();
        if (atomicAdd(cnt, 1u) == 63u) {   // last block: deterministic ordered sum
            __threadfence();
            float tot = 0.f;
            for (int i = 0; i < 64; ++i) tot += bsums[i];
            out[0] = tot * (1.0f / (4.0f * (float)Bb));
        }
    }
}

extern "C" void kernel_launch(void* const* d_in, const int* in_sizes, int n_in,
                              void* d_out, int out_size, void* d_ws, size_t ws_size,
                              hipStream_t stream) {
    (void)n_in; (void)out_size; (void)ws_size;
    const float* user    = (const float*)d_in[0];
    const float* item    = (const float*)d_in[1];
    const float* bias    = (const float*)d_in[2];
    const int*   posids  = (const int*)d_in[3];
    const int*   sampled = (const int*)d_in[4];
    const int*   ntries  = (const int*)d_in[5];
    float* out = (float*)d_out;

    const int V = in_sizes[2];
    const float invLogV1 = 1.0f / logf((float)V + 1.0f);
    const int nbmw = (V + 31) / 32;
    const int zb = (nbmw + 1023) / 1024;

    char* p = (char*)d_ws;
    auto alloc = [&](size_t bytes) {
        char* r = p;
        p += (bytes + 255) & ~(size_t)255;
        return r;
    };
    unsigned short* Ebf     = (unsigned short*)alloc((size_t)Ss * Dd * 2);
    unsigned short* Ubf     = (unsigned short*)alloc((size_t)Bb * Dd * 2);
    float*          c2      = (float*)alloc((size_t)Ss * 4);
    float*          partial = (float*)alloc((size_t)Bb * STILES * 4);
    unsigned int*   bm      = (unsigned int*)alloc((size_t)nbmw * 4);
    float*          bsums   = (float*)alloc(64 * 4);
    unsigned int*   cnt     = (unsigned int*)alloc(256);

    k_prep<<<SAMP_BLOCKS + zb + USER_BLOCKS + C2_BLOCKS, 256, 0, stream>>>(
        user, item, bias, sampled, ntries, Ebf, Ubf, c2, bm, cnt, invLogV1, nbmw, zb);
    ssl_main<<<dim3(STILES, Bb / BN), 256, 0, stream>>>(Ebf, Ubf, c2, partial);
    k_final<<<Bb / 64, 256, 0, stream>>>(user, item, bias, posids, ntries,
                                         partial, bm, bsums, cnt, out, invLogV1);
}